// Round 3
// baseline (577.470 us; speedup 1.0000x reference)
//
#include <hip/hip_runtime.h>
#include <math.h>

// Problem constants (B=2, S=2048, D=1024, R=224)
#define D_DIM 1024
#define R_DIM 224
#define N_TOK 4096
#define T_ROW 8
#define ROW_BLOCKS (N_TOK / T_ROW)   // 512
#define T_COL 32
#define DC 128                        // D-chunk staged in LDS for col pass

// ---------------------------------------------------------------------------
// Kernel 0: counting-sort tokens by row id; also zero the output scalar.
// ---------------------------------------------------------------------------
__global__ __launch_bounds__(1024) void sort_kernel(
    const int* __restrict__ rid, int* __restrict__ sorted,
    int* __restrict__ cnt, int* __restrict__ off, float* __restrict__ out)
{
    __shared__ int h[R_DIM];
    __shared__ int cur[R_DIM];
    const int tid = threadIdx.x;
    for (int i = tid; i < R_DIM; i += 1024) h[i] = 0;
    __syncthreads();
    for (int n = tid; n < N_TOK; n += 1024) atomicAdd(&h[rid[n]], 1);
    __syncthreads();
    if (tid == 0) {
        int acc = 0;
        for (int i = 0; i < R_DIM; ++i) {
            cur[i] = acc;
            off[i] = acc;
            cnt[i] = h[i];
            acc += h[i];
        }
        out[0] = 0.0f;
    }
    __syncthreads();
    for (int n = tid; n < N_TOK; n += 1024) {
        int p = atomicAdd(&cur[rid[n]], 1);
        sorted[p] = n;
    }
}

// ---------------------------------------------------------------------------
// Col pass: one block handles up to TT tokens of row rho against W=[D,R].
// Thread k (k<224) owns logit column k; acc[t] is statically indexed.
// ---------------------------------------------------------------------------
template <int TT>
__device__ __forceinline__ void col_pass(
    const float* __restrict__ hs, const float* __restrict__ W,
    const float* __restrict__ bcr, const int* __restrict__ sorted_base,
    const int* __restrict__ cid, int tcount,
    float* __restrict__ ldsA, float* __restrict__ ldsL, float* __restrict__ blk_sum)
{
    const int tid = threadIdx.x;
    float acc[TT];
#pragma unroll
    for (int t = 0; t < TT; ++t) acc[t] = 0.0f;

    for (int dc = 0; dc < D_DIM; dc += DC) {
        __syncthreads();   // protect ldsA from previous phase readers
        // stage hs chunk [TT][DC] as float4 (zero-padded past tcount)
        for (int i = tid; i < TT * (DC / 4); i += 256) {
            int t = i / (DC / 4);
            int dd = (i - t * (DC / 4)) * 4;
            float4 v = make_float4(0.f, 0.f, 0.f, 0.f);
            if (t < tcount) {
                int n = sorted_base[t];
                v = *reinterpret_cast<const float4*>(&hs[(size_t)n * D_DIM + dc + dd]);
            }
            *reinterpret_cast<float4*>(&ldsA[t * DC + dd]) = v;
        }
        __syncthreads();
        if (tid < R_DIM) {
            const float* Wd = W + (size_t)dc * R_DIM + tid;
            for (int d = 0; d < DC; d += 4) {
                float w0 = Wd[(d + 0) * R_DIM];
                float w1 = Wd[(d + 1) * R_DIM];
                float w2 = Wd[(d + 2) * R_DIM];
                float w3 = Wd[(d + 3) * R_DIM];
#pragma unroll
                for (int t = 0; t < TT; ++t) {
                    const float4 h4 = *reinterpret_cast<const float4*>(&ldsA[t * DC + d]);
                    acc[t] = fmaf(h4.x, w0, acc[t]);
                    acc[t] = fmaf(h4.y, w1, acc[t]);
                    acc[t] = fmaf(h4.z, w2, acc[t]);
                    acc[t] = fmaf(h4.w, w3, acc[t]);
                }
            }
        }
    }
    __syncthreads();
    if (tid < R_DIM) {
        float bk = bcr[tid];
#pragma unroll
        for (int t = 0; t < TT; ++t)
            if (t < tcount) ldsL[t * R_DIM + tid] = acc[t] + bk;
    }
    __syncthreads();
    // softmax: 32 groups of 8 lanes, group t handles token t
    const int t = tid >> 3;
    const int l = tid & 7;
    if (t < tcount) {
        float m = -1e30f;
        for (int k = l; k < R_DIM; k += 8) m = fmaxf(m, ldsL[t * R_DIM + k]);
#pragma unroll
        for (int s = 4; s; s >>= 1) m = fmaxf(m, __shfl_xor(m, s, 8));
        float sum = 0.0f;
        for (int k = l; k < R_DIM; k += 8) sum += __expf(ldsL[t * R_DIM + k] - m);
#pragma unroll
        for (int s = 4; s; s >>= 1) sum += __shfl_xor(sum, s, 8);
        if (l == 0) {
            int n = sorted_base[t];
            float nll = -(ldsL[t * R_DIM + cid[n]] - m - __logf(sum));
            atomicAdd(blk_sum, nll);
        }
    }
}

// ---------------------------------------------------------------------------
// Fused kernel: blocks [0,224) = col rows (long work first), rest = row CE.
// ---------------------------------------------------------------------------
__global__ __launch_bounds__(256) void fused_kernel(
    const float* __restrict__ hs, const float* __restrict__ w_row,
    const float* __restrict__ b_row, const float* __restrict__ w_col,
    const float* __restrict__ b_col, const int* __restrict__ rid,
    const int* __restrict__ cid, const int* __restrict__ sorted,
    const int* __restrict__ cnt, const int* __restrict__ off,
    float* __restrict__ out)
{
    __shared__ float ldsA[T_ROW * D_DIM];   // 32 KB: row hs staging / col chunk
    __shared__ float ldsL[T_COL * R_DIM];   // 28 KB: logits
    __shared__ float blk_sum;
    const int bid = blockIdx.x;
    const int tid = threadIdx.x;
    if (tid == 0) blk_sum = 0.0f;

    if (bid < R_DIM) {
        // ------------------- column loss for row id rho -------------------
        const int rho = bid;
        const int base = off[rho];
        const int n_tok = cnt[rho];
        const float* W = w_col + (size_t)rho * D_DIM * R_DIM;
        const float* bcr = b_col + rho * R_DIM;
        for (int p = 0; p < n_tok; p += T_COL) {
            int tc = min(T_COL, n_tok - p);
            int tt = (tc + 7) & ~7;
            const int* sb = sorted + base + p;
            switch (tt) {
                case 8:  col_pass<8>(hs, W, bcr, sb, cid, tc, ldsA, ldsL, &blk_sum); break;
                case 16: col_pass<16>(hs, W, bcr, sb, cid, tc, ldsA, ldsL, &blk_sum); break;
                case 24: col_pass<24>(hs, W, bcr, sb, cid, tc, ldsA, ldsL, &blk_sum); break;
                default: col_pass<32>(hs, W, bcr, sb, cid, tc, ldsA, ldsL, &blk_sum); break;
            }
        }
        __syncthreads();
        if (tid == 0) atomicAdd(out, blk_sum * (1.0f / N_TOK));
    } else {
        // ----------------------- row loss, 8 tokens -----------------------
        const int n0 = (bid - R_DIM) * T_ROW;
        for (int i = tid; i < T_ROW * (D_DIM / 4); i += 256) {
            *reinterpret_cast<float4*>(&ldsA[i * 4]) =
                *reinterpret_cast<const float4*>(&hs[(size_t)n0 * D_DIM + i * 4]);
        }
        __syncthreads();
        if (tid < R_DIM) {
            float acc[T_ROW];
#pragma unroll
            for (int t = 0; t < T_ROW; ++t) acc[t] = 0.0f;
            const float* Wd = w_row + tid;
            for (int d = 0; d < D_DIM; d += 4) {
                float w0 = Wd[(d + 0) * R_DIM];
                float w1 = Wd[(d + 1) * R_DIM];
                float w2 = Wd[(d + 2) * R_DIM];
                float w3 = Wd[(d + 3) * R_DIM];
#pragma unroll
                for (int t = 0; t < T_ROW; ++t) {
                    const float4 h4 = *reinterpret_cast<const float4*>(&ldsA[t * D_DIM + d]);
                    acc[t] = fmaf(h4.x, w0, acc[t]);
                    acc[t] = fmaf(h4.y, w1, acc[t]);
                    acc[t] = fmaf(h4.z, w2, acc[t]);
                    acc[t] = fmaf(h4.w, w3, acc[t]);
                }
            }
            float bk = b_row[tid];
#pragma unroll
            for (int t = 0; t < T_ROW; ++t) ldsL[t * R_DIM + tid] = acc[t] + bk;
        }
        __syncthreads();
        // softmax: 8 groups of 32 lanes
        const int t = tid >> 5;
        const int l = tid & 31;
        {
            float m = -1e30f;
            for (int k = l; k < R_DIM; k += 32) m = fmaxf(m, ldsL[t * R_DIM + k]);
#pragma unroll
            for (int s = 16; s; s >>= 1) m = fmaxf(m, __shfl_xor(m, s, 32));
            float sum = 0.0f;
            for (int k = l; k < R_DIM; k += 32) sum += __expf(ldsL[t * R_DIM + k] - m);
#pragma unroll
            for (int s = 16; s; s >>= 1) sum += __shfl_xor(sum, s, 32);
            if (l == 0) {
                int n = n0 + t;
                float nll = -(ldsL[t * R_DIM + rid[n]] - m - __logf(sum));
                atomicAdd(&blk_sum, nll);
            }
        }
        __syncthreads();
        if (tid == 0) atomicAdd(out, blk_sum * (1.0f / N_TOK));
    }
}

extern "C" void kernel_launch(void* const* d_in, const int* in_sizes, int n_in,
                              void* d_out, int out_size, void* d_ws, size_t ws_size,
                              hipStream_t stream)
{
    const float* hs    = (const float*)d_in[0];   // [2,2048,1024]
    const float* w_row = (const float*)d_in[1];   // [1024,224]
    const float* b_row = (const float*)d_in[2];   // [224]
    const float* w_col = (const float*)d_in[3];   // [224,1024,224]
    const float* b_col = (const float*)d_in[4];   // [224,224]
    const int* rid     = (const int*)d_in[5];     // [2,2048]
    const int* cid     = (const int*)d_in[6];     // [2,2048]
    float* out = (float*)d_out;

    int* sorted = (int*)d_ws;             // [4096]
    int* cnt    = sorted + N_TOK;         // [224]
    int* off    = cnt + R_DIM;            // [224]

    hipLaunchKernelGGL(sort_kernel, dim3(1), dim3(1024), 0, stream,
                       rid, sorted, cnt, off, out);
    hipLaunchKernelGGL(fused_kernel, dim3(R_DIM + ROW_BLOCKS), dim3(256), 0, stream,
                       hs, w_row, b_row, w_col, b_col, rid, cid, sorted, cnt, off, out);
}

// Round 4
// 424.152 us; speedup vs baseline: 1.3615x; 1.3615x over previous
//
#include <hip/hip_runtime.h>
#include <math.h>

// Problem constants (B=2, S=2048, D=1024, R=224)
#define D_DIM 1024
#define R_DIM 224
#define N_TOK 4096
#define TCH 32                       // col-pass token chunk
#define RT  16                       // row tokens per block
#define DCH 128                      // D staged per LDS chunk
#define COL_BLOCKS R_DIM             // 224
#define ROW_BLOCKS (N_TOK / RT)      // 256

// ---------------------------------------------------------------------------
// Kernel 0: counting-sort tokens by row id; also zero the output scalar.
// ---------------------------------------------------------------------------
__global__ __launch_bounds__(1024) void sort_kernel(
    const int* __restrict__ rid, int* __restrict__ sorted,
    int* __restrict__ cnt, int* __restrict__ off, float* __restrict__ out)
{
    __shared__ int h[R_DIM];
    __shared__ int cur[R_DIM];
    const int tid = threadIdx.x;
    for (int i = tid; i < R_DIM; i += 1024) h[i] = 0;
    __syncthreads();
    for (int n = tid; n < N_TOK; n += 1024) atomicAdd(&h[rid[n]], 1);
    __syncthreads();
    if (tid == 0) {
        int acc = 0;
        for (int i = 0; i < R_DIM; ++i) {
            cur[i] = acc;
            off[i] = acc;
            cnt[i] = h[i];
            acc += h[i];
        }
        out[0] = 0.0f;
    }
    __syncthreads();
    for (int n = tid; n < N_TOK; n += 1024) {
        int p = atomicAdd(&cur[rid[n]], 1);
        sorted[p] = n;
    }
}

// ---------------------------------------------------------------------------
// Col chunk: 512 threads = 2 groups of 256; group g owns D-half [g*512,+512).
// Thread k (<224) owns logit column k; acc[t] statically indexed (TT template).
// Partial logits from the two groups are reduced in LDS (2 barrier phases).
// ---------------------------------------------------------------------------
template <int TT>
__device__ __forceinline__ void col_chunk(
    const float* __restrict__ hs, const float* __restrict__ W,
    const float* __restrict__ bcr, const int* __restrict__ sb,
    const int* __restrict__ cid, int tcount, int g, int k,
    float (*ldsA)[TCH][DCH], float* __restrict__ ldsL,
    float* __restrict__ blk_sum)
{
    float acc[TT];
#pragma unroll
    for (int t = 0; t < TT; ++t) acc[t] = 0.0f;

    const int dbase = g * (D_DIM / 2);
    for (int it = 0; it < (D_DIM / 2) / DCH; ++it) {   // 4 chunks of 128
        __syncthreads();                                // ldsA safe to overwrite
        const int d0 = dbase + it * DCH;
        for (int i = k; i < TT * (DCH / 4); i += 256) {
            int t  = i / (DCH / 4);
            int dd = (i - t * (DCH / 4)) * 4;
            float4 v = make_float4(0.f, 0.f, 0.f, 0.f);
            if (t < tcount) {
                int n = sb[t];
                v = *reinterpret_cast<const float4*>(&hs[(size_t)n * D_DIM + d0 + dd]);
            }
            *reinterpret_cast<float4*>(&ldsA[g][t][dd]) = v;
        }
        __syncthreads();
        if (k < R_DIM) {
            const float* Wd = W + (size_t)d0 * R_DIM + k;
            for (int d = 0; d < DCH; d += 4) {
                float w0 = Wd[(d + 0) * R_DIM];
                float w1 = Wd[(d + 1) * R_DIM];
                float w2 = Wd[(d + 2) * R_DIM];
                float w3 = Wd[(d + 3) * R_DIM];
#pragma unroll
                for (int t = 0; t < TT; ++t) {
                    const float4 h4 = *reinterpret_cast<const float4*>(&ldsA[g][t][d]);
                    acc[t] = fmaf(h4.x, w0, acc[t]);
                    acc[t] = fmaf(h4.y, w1, acc[t]);
                    acc[t] = fmaf(h4.z, w2, acc[t]);
                    acc[t] = fmaf(h4.w, w3, acc[t]);
                }
            }
        }
    }
    // reduce the two D-halves into ldsL (deterministic, no atomics)
    __syncthreads();
    if (g == 0 && k < R_DIM) {
        float bk = bcr[k];
#pragma unroll
        for (int t = 0; t < TT; ++t) ldsL[t * R_DIM + k] = acc[t] + bk;
    }
    __syncthreads();
    if (g == 1 && k < R_DIM) {
#pragma unroll
        for (int t = 0; t < TT; ++t) ldsL[t * R_DIM + k] += acc[t];
    }
    __syncthreads();
    // softmax: 32 tokens × 16 lanes each
    const int t = threadIdx.x >> 4;
    const int l = threadIdx.x & 15;
    if (t < tcount) {
        float m = -1e30f;
        for (int kk = l; kk < R_DIM; kk += 16) m = fmaxf(m, ldsL[t * R_DIM + kk]);
#pragma unroll
        for (int s = 8; s; s >>= 1) m = fmaxf(m, __shfl_xor(m, s, 16));
        float sum = 0.0f;
        for (int kk = l; kk < R_DIM; kk += 16) sum += __expf(ldsL[t * R_DIM + kk] - m);
#pragma unroll
        for (int s = 8; s; s >>= 1) sum += __shfl_xor(sum, s, 16);
        if (l == 0) {
            int n = sb[t];
            float nll = -(ldsL[t * R_DIM + cid[n]] - m - __logf(sum));
            atomicAdd(blk_sum, nll);
        }
    }
}

// ---------------------------------------------------------------------------
// Fused kernel, 512 threads, 2 blocks/CU: blocks [0,224) col rows; rest row CE
// (16 tokens each, 2 groups of 8 tokens over full D).
// ---------------------------------------------------------------------------
__global__ __launch_bounds__(512, 4) void fused_kernel(
    const float* __restrict__ hs, const float* __restrict__ w_row,
    const float* __restrict__ b_row, const float* __restrict__ w_col,
    const float* __restrict__ b_col, const int* __restrict__ rid,
    const int* __restrict__ cid, const int* __restrict__ sorted,
    const int* __restrict__ cnt, const int* __restrict__ off,
    float* __restrict__ out)
{
    __shared__ float ldsA[2][TCH][DCH];   // 32 KB staging (per-group halves)
    __shared__ float ldsL[TCH * R_DIM];   // 28 KB logits
    __shared__ float blk_sum;
    const int bid = blockIdx.x;
    const int tid = threadIdx.x;
    const int g = tid >> 8;               // group 0/1
    const int k = tid & 255;
    if (tid == 0) blk_sum = 0.0f;
    __syncthreads();

    if (bid < COL_BLOCKS) {
        // ------------------- column loss for row id rho -------------------
        const int rho = bid;
        const int base = off[rho];
        const int n_tok = cnt[rho];
        const float* W = w_col + (size_t)rho * D_DIM * R_DIM;
        const float* bcr = b_col + rho * R_DIM;
        for (int p = 0; p < n_tok; p += TCH) {
            int tc = min(TCH, n_tok - p);
            int tt = (tc + 7) & ~7;
            const int* sb = sorted + base + p;
            switch (tt) {
                case 8:  col_chunk<8>(hs, W, bcr, sb, cid, tc, g, k, ldsA, ldsL, &blk_sum); break;
                case 16: col_chunk<16>(hs, W, bcr, sb, cid, tc, g, k, ldsA, ldsL, &blk_sum); break;
                case 24: col_chunk<24>(hs, W, bcr, sb, cid, tc, g, k, ldsA, ldsL, &blk_sum); break;
                default: col_chunk<32>(hs, W, bcr, sb, cid, tc, g, k, ldsA, ldsL, &blk_sum); break;
            }
        }
        __syncthreads();
        if (tid == 0) atomicAdd(out, blk_sum * (1.0f / N_TOK));
    } else {
        // --------------- row loss, 16 tokens (2 groups of 8) --------------
        const int n0 = (bid - COL_BLOCKS) * RT;
        float acc[8];
#pragma unroll
        for (int t = 0; t < 8; ++t) acc[t] = 0.0f;
        for (int it = 0; it < D_DIM / DCH; ++it) {    // 8 chunks of 128
            __syncthreads();
            const int d0 = it * DCH;
            {   // stage this group's 8 tokens × 128 d: exactly 1 float4/thread
                int t  = k >> 5;
                int dd = (k & 31) * 4;
                *reinterpret_cast<float4*>(&ldsA[g][t][dd]) =
                    *reinterpret_cast<const float4*>(
                        &hs[(size_t)(n0 + g * 8 + t) * D_DIM + d0 + dd]);
            }
            __syncthreads();
            if (k < R_DIM) {
                const float* Wd = w_row + (size_t)d0 * R_DIM + k;
                for (int d = 0; d < DCH; d += 4) {
                    float w0 = Wd[(d + 0) * R_DIM];
                    float w1 = Wd[(d + 1) * R_DIM];
                    float w2 = Wd[(d + 2) * R_DIM];
                    float w3 = Wd[(d + 3) * R_DIM];
#pragma unroll
                    for (int t = 0; t < 8; ++t) {
                        const float4 h4 = *reinterpret_cast<const float4*>(&ldsA[g][t][d]);
                        acc[t] = fmaf(h4.x, w0, acc[t]);
                        acc[t] = fmaf(h4.y, w1, acc[t]);
                        acc[t] = fmaf(h4.z, w2, acc[t]);
                        acc[t] = fmaf(h4.w, w3, acc[t]);
                    }
                }
            }
        }
        __syncthreads();
        if (k < R_DIM) {
            float bk = b_row[k];
#pragma unroll
            for (int t = 0; t < 8; ++t) ldsL[(g * 8 + t) * R_DIM + k] = acc[t] + bk;
        }
        __syncthreads();
        // softmax: 16 tokens × 32 lanes each
        const int t = tid >> 5;
        const int l = tid & 31;
        {
            float m = -1e30f;
            for (int kk = l; kk < R_DIM; kk += 32) m = fmaxf(m, ldsL[t * R_DIM + kk]);
#pragma unroll
            for (int s = 16; s; s >>= 1) m = fmaxf(m, __shfl_xor(m, s, 32));
            float sum = 0.0f;
            for (int kk = l; kk < R_DIM; kk += 32) sum += __expf(ldsL[t * R_DIM + kk] - m);
#pragma unroll
            for (int s = 16; s; s >>= 1) sum += __shfl_xor(sum, s, 32);
            if (l == 0) {
                int n = n0 + t;
                float nll = -(ldsL[t * R_DIM + rid[n]] - m - __logf(sum));
                atomicAdd(&blk_sum, nll);
            }
        }
        __syncthreads();
        if (tid == 0) atomicAdd(out, blk_sum * (1.0f / N_TOK));
    }
}

extern "C" void kernel_launch(void* const* d_in, const int* in_sizes, int n_in,
                              void* d_out, int out_size, void* d_ws, size_t ws_size,
                              hipStream_t stream)
{
    const float* hs    = (const float*)d_in[0];   // [2,2048,1024]
    const float* w_row = (const float*)d_in[1];   // [1024,224]
    const float* b_row = (const float*)d_in[2];   // [224]
    const float* w_col = (const float*)d_in[3];   // [224,1024,224]
    const float* b_col = (const float*)d_in[4];   // [224,224]
    const int* rid     = (const int*)d_in[5];     // [2,2048]
    const int* cid     = (const int*)d_in[6];     // [2,2048]
    float* out = (float*)d_out;

    int* sorted = (int*)d_ws;             // [4096]
    int* cnt    = sorted + N_TOK;         // [224]
    int* off    = cnt + R_DIM;            // [224]

    hipLaunchKernelGGL(sort_kernel, dim3(1), dim3(1024), 0, stream,
                       rid, sorted, cnt, off, out);
    hipLaunchKernelGGL(fused_kernel, dim3(COL_BLOCKS + ROW_BLOCKS), dim3(512), 0, stream,
                       hs, w_row, b_row, w_col, b_col, rid, cid, sorted, cnt, off, out);
}

// Round 6
// 343.654 us; speedup vs baseline: 1.6804x; 1.2342x over previous
//
#include <hip/hip_runtime.h>
#include <math.h>

// Problem constants (B=2, S=2048, D=1024, R=224)
#define D_DIM 1024
#define R_DIM 224
#define N_TOK 4096
#define KC 64                 // K-chunk staged per iteration
#define MT 128                // M-tile (tokens per chunk)
#define NTHREADS 448          // 7 waves; wave w owns cols [32w, 32w+32)
#define COL_BLOCKS R_DIM      // 224
#define ROW_BLOCKS (N_TOK / MT) // 32
#define GRID (COL_BLOCKS + ROW_BLOCKS) // 256 = #CUs

typedef short bf16x8 __attribute__((ext_vector_type(8)));
typedef short short4_t __attribute__((ext_vector_type(4)));
typedef float floatx4 __attribute__((ext_vector_type(4)));

__device__ __forceinline__ short f2bf(float f) {
    unsigned u = __float_as_uint(f);
    u += 0x7fffu + ((u >> 16) & 1u);   // round-to-nearest-even
    return (short)(u >> 16);
}

// ---------------------------------------------------------------------------
// Kernel 0: counting-sort tokens by row id; zero the output scalar.
// ---------------------------------------------------------------------------
__global__ __launch_bounds__(1024) void sort_kernel(
    const int* __restrict__ rid, int* __restrict__ sorted,
    int* __restrict__ cnt, int* __restrict__ off, float* __restrict__ out)
{
    __shared__ int h[R_DIM];
    __shared__ int cur[R_DIM];
    const int tid = threadIdx.x;
    for (int i = tid; i < R_DIM; i += 1024) h[i] = 0;
    __syncthreads();
    for (int n = tid; n < N_TOK; n += 1024) atomicAdd(&h[rid[n]], 1);
    __syncthreads();
    if (tid == 0) {
        int acc = 0;
        for (int i = 0; i < R_DIM; ++i) {
            cur[i] = acc; off[i] = acc; cnt[i] = h[i]; acc += h[i];
        }
        out[0] = 0.0f;
    }
    __syncthreads();
    for (int n = tid; n < N_TOK; n += 1024) {
        int p = atomicAdd(&cur[rid[n]], 1);
        sorted[p] = n;
    }
}

// ---------------------------------------------------------------------------
// Fused MFMA kernel. Blocks [0,224): col loss for row id rho (tokens gathered
// via counting sort). Blocks [224,256): row loss for 128 consecutive tokens.
// GEMM: C[m][n] = sum_k A[m][k] * B[k][n];  A = tokens x D (bf16, staged),
// B = W chunk D x R (bf16, transposed-staged). mfma_f32_16x16x32_bf16:
//   a[j] = A[l&15][(l>>4)*8+j]; b[j] = B[(l>>4)*8+j][l&15];
//   acc reg r -> C[(l>>4)*4+r][l&15]   (m89-verified layouts)
// LDS rows are 128B-strided -> XOR-swizzle byte ^= ((row&7)<<4)  (G4).
// ---------------------------------------------------------------------------
__global__ __launch_bounds__(NTHREADS) void fused_kernel(
    const float* __restrict__ hs, const float* __restrict__ w_row,
    const float* __restrict__ b_row, const float* __restrict__ w_col,
    const float* __restrict__ b_col, const int* __restrict__ rid,
    const int* __restrict__ cid, const int* __restrict__ sorted,
    const int* __restrict__ cnt, const int* __restrict__ off,
    float* __restrict__ out)
{
    __shared__ short A_sh[MT * KC];        // 16 KB  [row][k] swizzled
    __shared__ short B_sh[R_DIM * KC];     // 28 KB  [n][k]   swizzled
    __shared__ float Log_sh[16 * R_DIM];   // 14 KB  logits for one 16-row tile
    __shared__ float bias_sh[R_DIM];
    __shared__ int   tok_sh[MT];
    __shared__ float blk_sum;

    const int bid = blockIdx.x;
    const int tid = threadIdx.x;
    const int lane = tid & 63;
    const int wv = tid >> 6;              // 0..6
    const int lm = lane & 15;
    const int lg = lane >> 4;             // 0..3

    const bool is_row = (bid >= COL_BLOCKS);
    const int rho = is_row ? 0 : bid;
    const int tokbase = is_row ? (bid - COL_BLOCKS) * MT : off[rho];
    const int n_tok  = is_row ? MT : cnt[rho];
    const float* W    = is_row ? w_row : (w_col + (size_t)rho * D_DIM * R_DIM);
    const float* bias = is_row ? b_row : (b_col + (size_t)rho * R_DIM);

    if (tid == 0) blk_sum = 0.0f;
    for (int i = tid; i < R_DIM; i += NTHREADS) bias_sh[i] = bias[i];

    char* const Abp = (char*)A_sh;
    char* const Bbp = (char*)B_sh;

    const int n_chunks = (n_tok + MT - 1) / MT;
    for (int p = 0; p < n_chunks; ++p) {
        const int mlim = min(MT, n_tok - p * MT);   // valid tokens this chunk

        __syncthreads();
        if (tid < MT) {
            int gi = p * MT + tid;
            tok_sh[tid] = (gi < n_tok)
                ? (is_row ? (tokbase + gi) : sorted[tokbase + gi]) : -1;
        }

        floatx4 acc[8][2];
#pragma unroll
        for (int ms = 0; ms < 8; ++ms)
#pragma unroll
            for (int nt = 0; nt < 2; ++nt) acc[ms][nt] = (floatx4)0.0f;

        for (int kc = 0; kc < D_DIM / KC; ++kc) {
            const int K0 = kc * KC;
            __syncthreads();   // prev MFMA reads done before overwrite
            // ---- stage A: MT x KC bf16, 1 float4 -> short4 per task ----
            for (int i = tid; i < MT * (KC / 4); i += NTHREADS) {
                int row = i >> 4;
                int g = i & 15;                 // k-quad
                int tok = tok_sh[row];
                float4 hv = make_float4(0.f, 0.f, 0.f, 0.f);
                if (tok >= 0)
                    hv = *reinterpret_cast<const float4*>(
                        &hs[(size_t)tok * D_DIM + K0 + g * 4]);
                short4_t v = { f2bf(hv.x), f2bf(hv.y), f2bf(hv.z), f2bf(hv.w) };
                *reinterpret_cast<short4_t*>(
                    Abp + row * 128 + ((g * 8) ^ ((row & 7) << 4))) = v;
            }
            // ---- stage B^T: KC x R_DIM -> B_sh[n][k], k-quad x n-quad ----
            for (int i = tid; i < (KC / 4) * (R_DIM / 4); i += NTHREADS) {
                int nq = i % (R_DIM / 4);
                int kq = i / (R_DIM / 4);
                const float* src = W + (size_t)(K0 + kq * 4) * R_DIM + nq * 4;
                float4 r0 = *reinterpret_cast<const float4*>(src);
                float4 r1 = *reinterpret_cast<const float4*>(src + R_DIM);
                float4 r2 = *reinterpret_cast<const float4*>(src + 2 * R_DIM);
                float4 r3 = *reinterpret_cast<const float4*>(src + 3 * R_DIM);
                int n0 = nq * 4;
                short4_t v0 = { f2bf(r0.x), f2bf(r1.x), f2bf(r2.x), f2bf(r3.x) };
                short4_t v1 = { f2bf(r0.y), f2bf(r1.y), f2bf(r2.y), f2bf(r3.y) };
                short4_t v2 = { f2bf(r0.z), f2bf(r1.z), f2bf(r2.z), f2bf(r3.z) };
                short4_t v3 = { f2bf(r0.w), f2bf(r1.w), f2bf(r2.w), f2bf(r3.w) };
                *reinterpret_cast<short4_t*>(Bbp + (n0+0)*128 + ((kq*8) ^ (((n0+0)&7)<<4))) = v0;
                *reinterpret_cast<short4_t*>(Bbp + (n0+1)*128 + ((kq*8) ^ (((n0+1)&7)<<4))) = v1;
                *reinterpret_cast<short4_t*>(Bbp + (n0+2)*128 + ((kq*8) ^ (((n0+2)&7)<<4))) = v2;
                *reinterpret_cast<short4_t*>(Bbp + (n0+3)*128 + ((kq*8) ^ (((n0+3)&7)<<4))) = v3;
            }
            __syncthreads();
            // ---- MFMA: per ks, 2 b-frags + 8 a-frags, 16 MFMA ----
#pragma unroll
            for (int ks = 0; ks < 2; ++ks) {
                const int kbyte = ks * 64 + lg * 16;
                bf16x8 b0, b1;
                {
                    int n = wv * 32 + lm;
                    b0 = *reinterpret_cast<const bf16x8*>(
                        Bbp + n * 128 + (kbyte ^ ((n & 7) << 4)));
                    n += 16;
                    b1 = *reinterpret_cast<const bf16x8*>(
                        Bbp + n * 128 + (kbyte ^ ((n & 7) << 4)));
                }
#pragma unroll
                for (int ms = 0; ms < 8; ++ms) {
                    int row = ms * 16 + lm;
                    bf16x8 a = *reinterpret_cast<const bf16x8*>(
                        Abp + row * 128 + (kbyte ^ ((row & 7) << 4)));
                    acc[ms][0] = __builtin_amdgcn_mfma_f32_16x16x32_bf16(
                        a, b0, acc[ms][0], 0, 0, 0);
                    acc[ms][1] = __builtin_amdgcn_mfma_f32_16x16x32_bf16(
                        a, b1, acc[ms][1], 0, 0, 0);
                }
            }
        }

        // ---- epilogue: per 16-row tile, logits -> LDS, softmax, NLL ----
#pragma unroll
        for (int ms = 0; ms < 8; ++ms) {
            __syncthreads();   // Log_sh free (prev tile's softmax done)
#pragma unroll
            for (int nt = 0; nt < 2; ++nt) {
                int col = wv * 32 + nt * 16 + lm;
#pragma unroll
                for (int r = 0; r < 4; ++r) {
                    Log_sh[(lg * 4 + r) * R_DIM + col] = acc[ms][nt][r] + bias_sh[col];
                }
            }
            __syncthreads();
            const int mv = mlim - ms * 16;   // valid rows in this tile
            for (int rep = 0; rep < 3; ++rep) {
                int t = wv + rep * 7;
                if (t < 16 && t < mv) {
                    float m = -1e30f;
                    for (int c = lane; c < R_DIM; c += 64)
                        m = fmaxf(m, Log_sh[t * R_DIM + c]);
#pragma unroll
                    for (int s = 32; s; s >>= 1) m = fmaxf(m, __shfl_xor(m, s));
                    float sum = 0.0f;
                    for (int c = lane; c < R_DIM; c += 64)
                        sum += __expf(Log_sh[t * R_DIM + c] - m);
#pragma unroll
                    for (int s = 32; s; s >>= 1) sum += __shfl_xor(sum, s);
                    if (lane == 0) {
                        int n = tok_sh[ms * 16 + t];
                        int tgt = is_row ? rid[n] : cid[n];
                        float nll = -(Log_sh[t * R_DIM + tgt] - m - __logf(sum));
                        atomicAdd(&blk_sum, nll);
                    }
                }
            }
        }
    }
    __syncthreads();
    if (tid == 0) atomicAdd(out, blk_sum * (1.0f / N_TOK));
}

extern "C" void kernel_launch(void* const* d_in, const int* in_sizes, int n_in,
                              void* d_out, int out_size, void* d_ws, size_t ws_size,
                              hipStream_t stream)
{
    const float* hs    = (const float*)d_in[0];   // [2,2048,1024]
    const float* w_row = (const float*)d_in[1];   // [1024,224]
    const float* b_row = (const float*)d_in[2];   // [224]
    const float* w_col = (const float*)d_in[3];   // [224,1024,224]
    const float* b_col = (const float*)d_in[4];   // [224,224]
    const int* rid     = (const int*)d_in[5];     // [2,2048]
    const int* cid     = (const int*)d_in[6];     // [2,2048]
    float* out = (float*)d_out;

    int* sorted = (int*)d_ws;             // [4096]
    int* cnt    = sorted + N_TOK;         // [224]
    int* off    = cnt + R_DIM;            // [224]

    hipLaunchKernelGGL(sort_kernel, dim3(1), dim3(1024), 0, stream,
                       rid, sorted, cnt, off, out);
    hipLaunchKernelGGL(fused_kernel, dim3(GRID), dim3(NTHREADS), 0, stream,
                       hs, w_row, b_row, w_col, b_col, rid, cid, sorted, cnt, off, out);
}

// Round 7
// 342.065 us; speedup vs baseline: 1.6882x; 1.0046x over previous
//
#include <hip/hip_runtime.h>
#include <math.h>

// Problem constants (B=2, S=2048, D=1024, R=224)
#define D_DIM 1024
#define R_DIM 224
#define N_TOK 4096
#define KC 64                 // K-chunk per iteration
#define MT 128                // M-tile (tokens per chunk)
#define NTHREADS 448          // 7 waves; wave w owns cols [32w, 32w+32)
#define COL_BLOCKS R_DIM      // 224
#define ROW_BLOCKS (N_TOK / MT) // 32
#define GRID (COL_BLOCKS + ROW_BLOCKS) // 256 = #CUs

typedef short bf16x8 __attribute__((ext_vector_type(8)));
typedef short short8_t __attribute__((ext_vector_type(8)));
typedef float floatx4 __attribute__((ext_vector_type(4)));

__device__ __forceinline__ short f2bf(float f) {
    unsigned u = __float_as_uint(f);
    u += 0x7fffu + ((u >> 16) & 1u);   // round-to-nearest-even
    return (short)(u >> 16);
}

// LDS-only barrier: waits LDS ops but leaves global loads (vmcnt) in flight,
// unlike __syncthreads() which the compiler drains with vmcnt(0).
__device__ __forceinline__ void lds_barrier() {
    asm volatile("s_waitcnt lgkmcnt(0)" ::: "memory");
    __builtin_amdgcn_s_barrier();
}

// ---------------------------------------------------------------------------
// Kernel 0: counting-sort tokens by row id (parallel scan); zero out scalar.
// ---------------------------------------------------------------------------
__global__ __launch_bounds__(1024) void sort_kernel(
    const int* __restrict__ rid, int* __restrict__ sorted,
    int* __restrict__ cnt, int* __restrict__ off, float* __restrict__ out)
{
    __shared__ int h[256];
    __shared__ int sc[2][256];
    __shared__ int cur[R_DIM];
    const int tid = threadIdx.x;
    if (tid < 256) h[tid] = 0;
    __syncthreads();
    for (int n = tid; n < N_TOK; n += 1024) atomicAdd(&h[rid[n]], 1);
    __syncthreads();
    if (tid < 256) sc[0][tid] = h[tid];
    __syncthreads();
    int src = 0;
    for (int d = 1; d < 256; d <<= 1) {       // Hillis-Steele inclusive scan
        if (tid < 256) {
            int v = sc[src][tid];
            if (tid >= d) v += sc[src][tid - d];
            sc[src ^ 1][tid] = v;
        }
        __syncthreads();
        src ^= 1;
    }
    if (tid < R_DIM) {
        int o = sc[src][tid] - h[tid];        // exclusive
        off[tid] = o;
        cnt[tid] = h[tid];
        cur[tid] = o;
    }
    if (tid == 0) out[0] = 0.0f;
    __syncthreads();
    for (int n = tid; n < N_TOK; n += 1024) {
        int p = atomicAdd(&cur[rid[n]], 1);
        sorted[p] = n;
    }
}

// ---------------------------------------------------------------------------
// Fused MFMA kernel. Blocks [0,224): col loss for row id rho (tokens gathered
// via counting sort). Blocks [224,256): row loss for 128 consecutive tokens.
// A (tokens x D) staged bf16 in LDS (XOR-swizzled); B (W chunk D x 32cols per
// wave) loaded straight to registers (8x reuse via regs, no LDS B at all).
// mfma_f32_16x16x32_bf16 layouts (m89-verified):
//   a[j] = A[l&15][(l>>4)*8+j]; b[j] = B[(l>>4)*8+j][l&15];
//   acc reg r -> C[(l>>4)*4+r][l&15]
// ---------------------------------------------------------------------------
__global__ __launch_bounds__(NTHREADS) void fused_kernel(
    const float* __restrict__ hs, const float* __restrict__ w_row,
    const float* __restrict__ b_row, const float* __restrict__ w_col,
    const float* __restrict__ b_col, const int* __restrict__ rid,
    const int* __restrict__ cid, const int* __restrict__ sorted,
    const int* __restrict__ cnt, const int* __restrict__ off,
    float* __restrict__ out)
{
    __shared__ short A_sh[MT * KC];        // 16 KB  [row][k] swizzled
    __shared__ float Log_sh[16 * R_DIM];   // 14 KB  logits for one 16-row tile
    __shared__ float bias_sh[R_DIM];
    __shared__ int   tok_sh[MT];
    __shared__ float blk_sum;

    const int bid = blockIdx.x;
    const int tid = threadIdx.x;
    const int lane = tid & 63;
    const int wv = tid >> 6;              // 0..6
    const int lm = lane & 15;
    const int lg = lane >> 4;             // 0..3

    const bool is_row = (bid >= COL_BLOCKS);
    const int rho = is_row ? 0 : bid;
    const int tokbase = is_row ? (bid - COL_BLOCKS) * MT : off[rho];
    const int n_tok  = is_row ? MT : cnt[rho];
    const float* W    = is_row ? w_row : (w_col + (size_t)rho * D_DIM * R_DIM);
    const float* bias = is_row ? b_row : (b_col + (size_t)rho * R_DIM);

    if (tid == 0) blk_sum = 0.0f;
    for (int i = tid; i < R_DIM; i += NTHREADS) bias_sh[i] = bias[i];

    char* const Abp = (char*)A_sh;

    const int n_chunks = (n_tok + MT - 1) / MT;
    for (int p = 0; p < n_chunks; ++p) {
        const int mlim   = min(MT, n_tok - p * MT);  // valid tokens this chunk
        const int mtiles = (mlim + 15) >> 4;         // active 16-row tiles
        const int mrows  = mtiles << 4;

        lds_barrier();     // tok_sh/Log_sh free (prev chunk done)
        if (tid < MT) {
            int gi = p * MT + tid;
            tok_sh[tid] = (gi < n_tok)
                ? (is_row ? (tokbase + gi) : sorted[tokbase + gi]) : -1;
        }

        floatx4 acc[8][2];
#pragma unroll
        for (int ms = 0; ms < 8; ++ms)
#pragma unroll
            for (int nt = 0; nt < 2; ++nt) acc[ms][nt] = (floatx4)0.0f;

        for (int kc = 0; kc < D_DIM / KC; ++kc) {
            const int K0 = kc * KC;
            // ---- issue B loads for THIS chunk (latency hides under A-stage;
            //      lds_barrier does NOT drain vmcnt) ----
            float braw[2][2][8];
#pragma unroll
            for (int ks = 0; ks < 2; ++ks)
#pragma unroll
                for (int nt = 0; nt < 2; ++nt) {
                    const float* bp = W + (size_t)(K0 + ks * 32 + lg * 8) * R_DIM
                                        + (wv * 32 + nt * 16 + lm);
#pragma unroll
                    for (int j = 0; j < 8; ++j) braw[ks][nt][j] = bp[j * R_DIM];
                }

            lds_barrier();   // prev MFMA consumed A_sh; tok_sh visible
            // ---- stage A: mrows x KC bf16, 16B writes, XOR-swizzled ----
            for (int i = tid; i < mrows * (KC / 8); i += NTHREADS) {
                int row = i >> 3;
                int g8 = i & 7;               // 8-elem k-group
                int tok = tok_sh[row];
                float4 h0 = make_float4(0.f, 0.f, 0.f, 0.f);
                float4 h1 = make_float4(0.f, 0.f, 0.f, 0.f);
                if (tok >= 0) {
                    const float* hp = &hs[(size_t)tok * D_DIM + K0 + g8 * 8];
                    h0 = *reinterpret_cast<const float4*>(hp);
                    h1 = *reinterpret_cast<const float4*>(hp + 4);
                }
                short8_t v = { f2bf(h0.x), f2bf(h0.y), f2bf(h0.z), f2bf(h0.w),
                               f2bf(h1.x), f2bf(h1.y), f2bf(h1.z), f2bf(h1.w) };
                *reinterpret_cast<short8_t*>(
                    Abp + row * 128 + ((g8 * 16) ^ ((row & 7) << 4))) = v;
            }
            lds_barrier();   // A writes visible to all waves

            // ---- pack B frags from registers (waits the global loads) ----
            bf16x8 bfrag[2][2];
#pragma unroll
            for (int ks = 0; ks < 2; ++ks)
#pragma unroll
                for (int nt = 0; nt < 2; ++nt) {
                    bf16x8 v = { f2bf(braw[ks][nt][0]), f2bf(braw[ks][nt][1]),
                                 f2bf(braw[ks][nt][2]), f2bf(braw[ks][nt][3]),
                                 f2bf(braw[ks][nt][4]), f2bf(braw[ks][nt][5]),
                                 f2bf(braw[ks][nt][6]), f2bf(braw[ks][nt][7]) };
                    bfrag[ks][nt] = v;
                }
            // ---- MFMA over active tiles only ----
#pragma unroll
            for (int ks = 0; ks < 2; ++ks) {
                const int kbyte = ks * 64 + lg * 16;
#pragma unroll
                for (int ms = 0; ms < 8; ++ms) {
                    if (ms < mtiles) {
                        int row = ms * 16 + lm;
                        bf16x8 a = *reinterpret_cast<const bf16x8*>(
                            Abp + row * 128 + (kbyte ^ ((row & 7) << 4)));
                        acc[ms][0] = __builtin_amdgcn_mfma_f32_16x16x32_bf16(
                            a, bfrag[ks][0], acc[ms][0], 0, 0, 0);
                        acc[ms][1] = __builtin_amdgcn_mfma_f32_16x16x32_bf16(
                            a, bfrag[ks][1], acc[ms][1], 0, 0, 0);
                    }
                }
            }
        }

        // ---- epilogue: per active 16-row tile: logits -> LDS, softmax, NLL ----
#pragma unroll
        for (int ms = 0; ms < 8; ++ms) {
            if (ms < mtiles) {
                lds_barrier();   // Log_sh free (prev tile's softmax done)
#pragma unroll
                for (int nt = 0; nt < 2; ++nt) {
                    int col = wv * 32 + nt * 16 + lm;
#pragma unroll
                    for (int r = 0; r < 4; ++r) {
                        Log_sh[(lg * 4 + r) * R_DIM + col] =
                            acc[ms][nt][r] + bias_sh[col];
                    }
                }
                lds_barrier();
                const int mv = mlim - ms * 16;   // valid rows in this tile
                for (int rep = 0; rep < 3; ++rep) {
                    int t = wv + rep * 7;
                    if (t < 16 && t < mv) {
                        float m = -1e30f;
                        for (int c = lane; c < R_DIM; c += 64)
                            m = fmaxf(m, Log_sh[t * R_DIM + c]);
#pragma unroll
                        for (int s = 32; s; s >>= 1) m = fmaxf(m, __shfl_xor(m, s));
                        float sum = 0.0f;
                        for (int c = lane; c < R_DIM; c += 64)
                            sum += __expf(Log_sh[t * R_DIM + c] - m);
#pragma unroll
                        for (int s = 32; s; s >>= 1) sum += __shfl_xor(sum, s);
                        if (lane == 0) {
                            int n = tok_sh[ms * 16 + t];
                            int tgt = is_row ? rid[n] : cid[n];
                            float nll = -(Log_sh[t * R_DIM + tgt] - m - __logf(sum));
                            atomicAdd(&blk_sum, nll);
                        }
                    }
                }
            }
        }
    }
    __syncthreads();
    if (tid == 0) atomicAdd(out, blk_sum * (1.0f / N_TOK));
}

extern "C" void kernel_launch(void* const* d_in, const int* in_sizes, int n_in,
                              void* d_out, int out_size, void* d_ws, size_t ws_size,
                              hipStream_t stream)
{
    const float* hs    = (const float*)d_in[0];   // [2,2048,1024]
    const float* w_row = (const float*)d_in[1];   // [1024,224]
    const float* b_row = (const float*)d_in[2];   // [224]
    const float* w_col = (const float*)d_in[3];   // [224,1024,224]
    const float* b_col = (const float*)d_in[4];   // [224,224]
    const int* rid     = (const int*)d_in[5];     // [2,2048]
    const int* cid     = (const int*)d_in[6];     // [2,2048]
    float* out = (float*)d_out;

    int* sorted = (int*)d_ws;             // [4096]
    int* cnt    = sorted + N_TOK;         // [224]
    int* off    = cnt + R_DIM;            // [224]

    hipLaunchKernelGGL(sort_kernel, dim3(1), dim3(1024), 0, stream,
                       rid, sorted, cnt, off, out);
    hipLaunchKernelGGL(fused_kernel, dim3(GRID), dim3(NTHREADS), 0, stream,
                       hs, w_row, b_row, w_col, b_col, rid, cid, sorted, cnt, off, out);
}

// Round 8
// 338.380 us; speedup vs baseline: 1.7066x; 1.0109x over previous
//
#include <hip/hip_runtime.h>
#include <math.h>

// Problem constants (B=2, S=2048, D=1024, R=224)
#define D_DIM 1024
#define R_DIM 224
#define N_TOK 4096
#define KSPLIT 4
#define KRANGE (D_DIM / KSPLIT)        // 256
#define MCHUNK 32
#define NTHREADS 448                   // 7 waves; wave w owns cols [32w,32w+32)
#define COL_GRID (R_DIM * KSPLIT)      // 896
#define ROW_MBLK (N_TOK / MCHUNK)      // 128
#define ROW_GRID (ROW_MBLK * KSPLIT)   // 512
#define GRID2 (COL_GRID + ROW_GRID)    // 1408
#define L_FLOATS (N_TOK * R_DIM)       // 917504 per buffer

typedef short bf16x8 __attribute__((ext_vector_type(8)));
typedef short short8_t __attribute__((ext_vector_type(8)));
typedef float floatx4 __attribute__((ext_vector_type(4)));

__device__ __forceinline__ short f2bf(float f) {
    unsigned u = __float_as_uint(f);
    u += 0x7fffu + ((u >> 16) & 1u);   // round-to-nearest-even
    return (short)(u >> 16);
}

// ---------------------------------------------------------------------------
// Kernel 1: block 0 counting-sorts tokens by row id (parallel scan) and zeros
// out[0]; blocks 1..64 zero the 7.3 MB logits buffer.
// ---------------------------------------------------------------------------
__global__ __launch_bounds__(1024) void init_kernel(
    const int* __restrict__ rid, int* __restrict__ sorted,
    int* __restrict__ cnt, int* __restrict__ off,
    float* __restrict__ Lbuf, float* __restrict__ out)
{
    const int tid = threadIdx.x;
    if (blockIdx.x != 0) {
        // zero L: 2*4096*224 floats = 458752 float4 = 64 blocks * 7168
        const int zb = blockIdx.x - 1;
        float4* Lp = reinterpret_cast<float4*>(Lbuf);
        const int base = zb * 7168;
        for (int i = tid; i < 7168; i += 1024)
            Lp[base + i] = make_float4(0.f, 0.f, 0.f, 0.f);
        return;
    }
    __shared__ int h[256];
    __shared__ int sc[2][256];
    __shared__ int cur[R_DIM];
    if (tid < 256) h[tid] = 0;
    __syncthreads();
    for (int n = tid; n < N_TOK; n += 1024) atomicAdd(&h[rid[n]], 1);
    __syncthreads();
    if (tid < 256) sc[0][tid] = h[tid];
    __syncthreads();
    int src = 0;
    for (int d = 1; d < 256; d <<= 1) {      // Hillis-Steele inclusive scan
        if (tid < 256) {
            int v = sc[src][tid];
            if (tid >= d) v += sc[src][tid - d];
            sc[src ^ 1][tid] = v;
        }
        __syncthreads();
        src ^= 1;
    }
    if (tid < R_DIM) {
        int o = sc[src][tid] - h[tid];       // exclusive
        off[tid] = o;
        cnt[tid] = h[tid];
        cur[tid] = o;
    }
    if (tid == 0) out[0] = 0.0f;
    __syncthreads();
    for (int n = tid; n < N_TOK; n += 1024) {
        int p = atomicAdd(&cur[rid[n]], 1);
        sorted[p] = n;
    }
}

// ---------------------------------------------------------------------------
// Kernel 2: partial GEMMs -> atomicAdd into logits buffers.
// Blocks [0, 896): col GEMM for (rho = bid>>2, ksplit = bid&3).
// Blocks [896, 1408): row GEMM for (mblk = idx>>2, ksplit = idx&3).
// A (<=32 tokens x 256 K) staged once in LDS as bf16 (XOR-swizzled rows);
// B (W slice) loaded straight to registers inside a barrier-free K-loop.
// mfma_f32_16x16x32_bf16 layouts (m89-verified):
//   a[j]=A[l&15][(l>>4)*8+j]; b[j]=B[(l>>4)*8+j][l&15]; acc r -> C[(l>>4)*4+r][l&15]
// ---------------------------------------------------------------------------
__global__ __launch_bounds__(NTHREADS) void gemm_kernel(
    const float* __restrict__ hs, const float* __restrict__ w_row,
    const float* __restrict__ w_col, const int* __restrict__ sorted,
    const int* __restrict__ cnt, const int* __restrict__ off,
    float* __restrict__ Lrow, float* __restrict__ Lcol)
{
    __shared__ short A_sh[MCHUNK * KRANGE];   // 16 KB, rows of 512 B, swizzled
    __shared__ int tok_sh[MCHUNK];

    const int bid = blockIdx.x;
    const int tid = threadIdx.x;
    const int lane = tid & 63;
    const int wv = tid >> 6;          // 0..6
    const int lm = lane & 15;
    const int lg = lane >> 4;         // 0..3

    const bool is_row = (bid >= COL_GRID);
    int ksp, tokbase, n_tok;
    const float* W;
    float* Ldst;
    if (is_row) {
        int idx = bid - COL_GRID;
        ksp = idx & 3;
        tokbase = (idx >> 2) * MCHUNK;
        n_tok = MCHUNK;
        W = w_row;
        Ldst = Lrow;
    } else {
        int rho = bid >> 2;
        ksp = bid & 3;
        tokbase = off[rho];
        n_tok = cnt[rho];
        W = w_col + (size_t)rho * D_DIM * R_DIM;
        Ldst = Lcol;
    }
    const int K0 = ksp * KRANGE;
    char* const Abp = (char*)A_sh;
    const int col0 = wv * 32 + lm;    // frag nt at col0 + nt*16

    const int n_chunks = (n_tok + MCHUNK - 1) / MCHUNK;
    for (int p = 0; p < n_chunks; ++p) {
        __syncthreads();              // prev chunk's A/tok reads complete
        if (tid < MCHUNK) {
            int gi = p * MCHUNK + tid;
            tok_sh[tid] = (gi < n_tok)
                ? (is_row ? (tokbase + gi) : sorted[tokbase + gi]) : -1;
        }
        __syncthreads();
        // ---- stage A once: 32 rows x 256 K, 16B writes, swizzled ----
        for (int i = tid; i < MCHUNK * (KRANGE / 8); i += NTHREADS) {
            int row = i >> 5;         // 32 8-elem groups per row
            int g8 = i & 31;
            int tok = tok_sh[row];
            float4 h0 = make_float4(0.f, 0.f, 0.f, 0.f);
            float4 h1 = make_float4(0.f, 0.f, 0.f, 0.f);
            if (tok >= 0) {
                const float* hp = &hs[(size_t)tok * D_DIM + K0 + g8 * 8];
                h0 = *reinterpret_cast<const float4*>(hp);
                h1 = *reinterpret_cast<const float4*>(hp + 4);
            }
            short8_t v = { f2bf(h0.x), f2bf(h0.y), f2bf(h0.z), f2bf(h0.w),
                           f2bf(h1.x), f2bf(h1.y), f2bf(h1.z), f2bf(h1.w) };
            *reinterpret_cast<short8_t*>(
                Abp + row * 512 + ((g8 * 16) ^ ((row & 7) << 4))) = v;
        }
        __syncthreads();

        // ---- barrier-free K loop: 8 steps of K=32 ----
        floatx4 acc[2][2];
#pragma unroll
        for (int ms = 0; ms < 2; ++ms)
#pragma unroll
            for (int nt = 0; nt < 2; ++nt) acc[ms][nt] = (floatx4)0.0f;

        for (int ks = 0; ks < 8; ++ks) {
            const float* bp = W + (size_t)(K0 + ks * 32 + lg * 8) * R_DIM + col0;
            float braw0[8], braw1[8];
#pragma unroll
            for (int j = 0; j < 8; ++j) braw0[j] = bp[j * R_DIM];
#pragma unroll
            for (int j = 0; j < 8; ++j) braw1[j] = bp[j * R_DIM + 16];
            bf16x8 bf0 = { f2bf(braw0[0]), f2bf(braw0[1]), f2bf(braw0[2]), f2bf(braw0[3]),
                           f2bf(braw0[4]), f2bf(braw0[5]), f2bf(braw0[6]), f2bf(braw0[7]) };
            bf16x8 bf1 = { f2bf(braw1[0]), f2bf(braw1[1]), f2bf(braw1[2]), f2bf(braw1[3]),
                           f2bf(braw1[4]), f2bf(braw1[5]), f2bf(braw1[6]), f2bf(braw1[7]) };
            const int kbyte = ks * 64 + lg * 16;
#pragma unroll
            for (int ms = 0; ms < 2; ++ms) {
                int row = ms * 16 + lm;
                bf16x8 a = *reinterpret_cast<const bf16x8*>(
                    Abp + row * 512 + (kbyte ^ ((row & 7) << 4)));
                acc[ms][0] = __builtin_amdgcn_mfma_f32_16x16x32_bf16(a, bf0, acc[ms][0], 0, 0, 0);
                acc[ms][1] = __builtin_amdgcn_mfma_f32_16x16x32_bf16(a, bf1, acc[ms][1], 0, 0, 0);
            }
        }

        // ---- epilogue: atomicAdd partial logits ----
#pragma unroll
        for (int ms = 0; ms < 2; ++ms)
#pragma unroll
            for (int r = 0; r < 4; ++r) {
                int mloc = ms * 16 + lg * 4 + r;
                int tok = tok_sh[mloc];
                if (tok >= 0) {
                    atomicAdd(&Ldst[(size_t)tok * R_DIM + col0], acc[ms][0][r]);
                    atomicAdd(&Ldst[(size_t)tok * R_DIM + col0 + 16], acc[ms][1][r]);
                }
            }
    }
}

// ---------------------------------------------------------------------------
// Kernel 3: per-token softmax + NLL from the logits buffers; block-reduced
// atomicAdd of (sum_row + sum_col)/N into out[0]. One wave per token.
// ---------------------------------------------------------------------------
__global__ __launch_bounds__(256) void loss_kernel(
    const float* __restrict__ Lrow, const float* __restrict__ Lcol,
    const float* __restrict__ b_row, const float* __restrict__ b_col,
    const int* __restrict__ rid, const int* __restrict__ cid,
    float* __restrict__ out)
{
    __shared__ float wsum[4];
    const int tid = threadIdx.x;
    const int lane = tid & 63;
    const int wv = tid >> 6;
    const int gw = blockIdx.x * 4 + wv;      // 512 waves total
    float accum = 0.0f;

    for (int n = gw; n < N_TOK; n += 512) {
        const int rt = rid[n];
        const int ct = cid[n];
#pragma unroll
        for (int part = 0; part < 2; ++part) {
            const float* Lp = (part == 0 ? Lrow : Lcol) + (size_t)n * R_DIM;
            const float* bp = (part == 0) ? b_row : (b_col + (size_t)rt * R_DIM);
            const int tgt = (part == 0) ? rt : ct;
            float v0 = Lp[lane] + bp[lane];
            float v1 = Lp[lane + 64] + bp[lane + 64];
            float v2 = Lp[lane + 128] + bp[lane + 128];
            float v3 = (lane < 32) ? (Lp[lane + 192] + bp[lane + 192]) : -1e30f;
            float m = fmaxf(fmaxf(v0, v1), fmaxf(v2, v3));
#pragma unroll
            for (int s = 32; s; s >>= 1) m = fmaxf(m, __shfl_xor(m, s));
            float sum = __expf(v0 - m) + __expf(v1 - m) + __expf(v2 - m)
                      + ((lane < 32) ? __expf(v3 - m) : 0.0f);
#pragma unroll
            for (int s = 32; s; s >>= 1) sum += __shfl_xor(sum, s);
            float tl = Lp[tgt] + bp[tgt];    // broadcast read, same all lanes
            accum += -(tl - m - __logf(sum));
        }
    }
    if (lane == 0) wsum[wv] = accum;
    __syncthreads();
    if (tid == 0)
        atomicAdd(out, (wsum[0] + wsum[1] + wsum[2] + wsum[3]) * (1.0f / N_TOK));
}

extern "C" void kernel_launch(void* const* d_in, const int* in_sizes, int n_in,
                              void* d_out, int out_size, void* d_ws, size_t ws_size,
                              hipStream_t stream)
{
    const float* hs    = (const float*)d_in[0];   // [2,2048,1024]
    const float* w_row = (const float*)d_in[1];   // [1024,224]
    const float* b_row = (const float*)d_in[2];   // [224]
    const float* w_col = (const float*)d_in[3];   // [224,1024,224]
    const float* b_col = (const float*)d_in[4];   // [224,224]
    const int* rid     = (const int*)d_in[5];     // [2,2048]
    const int* cid     = (const int*)d_in[6];     // [2,2048]
    float* out = (float*)d_out;

    // ws layout: Lrow [4096*224] f32, Lcol [4096*224] f32, sorted, cnt, off
    float* Lrow = (float*)d_ws;
    float* Lcol = Lrow + L_FLOATS;
    int* sorted = (int*)(Lcol + L_FLOATS);
    int* cnt    = sorted + N_TOK;
    int* off    = cnt + R_DIM;

    hipLaunchKernelGGL(init_kernel, dim3(65), dim3(1024), 0, stream,
                       rid, sorted, cnt, off, Lrow, out);
    hipLaunchKernelGGL(gemm_kernel, dim3(GRID2), dim3(NTHREADS), 0, stream,
                       hs, w_row, w_col, sorted, cnt, off, Lrow, Lcol);
    hipLaunchKernelGGL(loss_kernel, dim3(128), dim3(256), 0, stream,
                       Lrow, Lcol, b_row, b_col, rid, cid, out);
}